// Round 8
// baseline (336.420 us; speedup 1.0000x reference)
//
#include <hip/hip_runtime.h>

#define N_USERS 100000
#define N_ITEMS 50000
#define N_NODES 150000
#define NEDGES  4000000
#define EMB     64
#define BATCH   16384

#define RSHIFT  9
#define RPB     512                          // rows per bucket
#define NBKT    ((N_NODES + RPB - 1) / RPB)  // 293
#define BCAP    24576                        // max edges/bucket

#define PC_BS   1024
#define PC_CH   16384
#define PC_EPT  (PC_CH / PC_BS)                 // 16 edges/thread
#define PC_NWG  ((NEDGES + PC_CH - 1) / PC_CH)  // 245

#define CHROWS  32
#define NCHUNK  ((N_NODES + CHROWS - 1) / CHROWS)

// ---------------- helpers ----------------

__device__ __forceinline__ unsigned short f2b(float f) {  // fp32 -> bf16 RNE
    unsigned u = __float_as_uint(f);
    return (unsigned short)((u + 0x7FFFu + ((u >> 16) & 1u)) >> 16);
}
__device__ __forceinline__ float b2f_lo(unsigned v) { return __uint_as_float(v << 16); }
__device__ __forceinline__ float b2f_hi(unsigned v) { return __uint_as_float(v & 0xFFFF0000u); }

__device__ __forceinline__ void acc8(float* a, uint4 v) {
    a[0] += b2f_lo(v.x); a[1] += b2f_hi(v.x);
    a[2] += b2f_lo(v.y); a[3] += b2f_hi(v.y);
    a[4] += b2f_lo(v.z); a[5] += b2f_hi(v.z);
    a[6] += b2f_lo(v.w); a[7] += b2f_hi(v.w);
}

// ---------------- CSR build ----------------

__global__ void k_zero(int* __restrict__ bcursor, int* __restrict__ ghist) {
    int i = blockIdx.x * blockDim.x + threadIdx.x;
    if (i < NBKT) bcursor[i] = 0;
    if (i < 256) ghist[i] = 0;
}

// LDS-staged bucket partition; edges cached in registers across the two passes
__global__ __launch_bounds__(PC_BS) void k_partC(const int* __restrict__ erow,
                                                 const int* __restrict__ ecol,
                                                 int* __restrict__ bcursor,
                                                 unsigned* __restrict__ tmp) {
    __shared__ int cnt[NBKT];
    __shared__ int base_[NBKT];
    const int t = threadIdx.x;
    for (int i = t; i < NBKT; i += PC_BS) cnt[i] = 0;
    __syncthreads();
    const int e0 = blockIdx.x * PC_CH;
    int rr[PC_EPT], cc[PC_EPT];
#pragma unroll
    for (int k = 0; k < PC_EPT; ++k) {
        int e = e0 + t + k * PC_BS;
        if (e < NEDGES) {
            rr[k] = erow[e];
            cc[k] = ecol[e];
            atomicAdd(&cnt[rr[k] >> RSHIFT], 1);
        } else rr[k] = -1;
    }
    __syncthreads();
    for (int i = t; i < NBKT; i += PC_BS) {
        base_[i] = cnt[i] ? atomicAdd(&bcursor[i], cnt[i]) : 0;
        cnt[i] = 0;
    }
    __syncthreads();
#pragma unroll
    for (int k = 0; k < PC_EPT; ++k) {
        if (rr[k] >= 0) {
            int b = rr[k] >> RSHIFT;
            int pos = base_[b] + atomicAdd(&cnt[b], 1);
            if (pos < BCAP)
                tmp[(size_t)b * BCAP + pos] =
                    ((unsigned)(rr[k] & (RPB - 1)) << 18) | (unsigned)cc[k];
        }
    }
}

// scan of per-bucket totals
__global__ __launch_bounds__(512) void k_bscan(const int* __restrict__ bcursor,
                                               int* __restrict__ bbase,
                                               int* __restrict__ rowptr) {
    __shared__ int s[512];
    const int t = threadIdx.x;
    int v = 0;
    if (t < NBKT) { v = bcursor[t]; if (v > BCAP) v = BCAP; }
    s[t] = v;
    __syncthreads();
    for (int off = 1; off < 512; off <<= 1) {
        int u = (t >= off) ? s[t - off] : 0;
        __syncthreads();
        s[t] += u;
        __syncthreads();
    }
    if (t < NBKT) bbase[t] = s[t] - v;  // exclusive
    if (t == 511) { bbase[NBKT] = s[511]; rowptr[N_NODES] = s[511]; }
}

// fused: row count (LDS) -> scan -> rowptr+dinv/s2/srt -> place edges
// also accumulates global degree histogram (for degree-sorted permutation)
__global__ __launch_bounds__(512) void k_rows_place(const unsigned* __restrict__ tmp,
                                                    const int* __restrict__ bcursor,
                                                    const int* __restrict__ bbase,
                                                    int* __restrict__ rowptr,
                                                    float* __restrict__ dinv,
                                                    float* __restrict__ s2,
                                                    float* __restrict__ srt,
                                                    int* __restrict__ csrc,
                                                    int* __restrict__ ghist) {
    __shared__ int rc[RPB];
    __shared__ int pre[RPB];
    __shared__ int dh[256];
    const int b = blockIdx.x;
    const int t = threadIdx.x;
    rc[t] = 0;
    if (t < 256) dh[t] = 0;
    __syncthreads();
    int n = bcursor[b]; if (n > BCAP) n = BCAP;
    const unsigned* tp = tmp + (size_t)b * BCAP;
    for (int i = t; i < n; i += 512) atomicAdd(&rc[tp[i] >> 18], 1);
    __syncthreads();
    int my = rc[t];
    pre[t] = my;
    __syncthreads();
    for (int off = 1; off < 512; off <<= 1) {
        int u = (t >= off) ? pre[t - off] : 0;
        __syncthreads();
        pre[t] += u;
        __syncthreads();
    }
    int ex   = pre[t] - my;
    int base = bbase[b];
    int r = b * RPB + t;
    if (r < N_NODES) {
        float sr = sqrtf((float)my) + 1e-6f;   // 1/dinv
        float dv = 1.0f / sr;
        rowptr[r] = base + ex;
        dinv[r] = dv;
        s2[r]   = dv * dv;
        srt[r]  = sr;
        int bin = my > 255 ? 255 : my;
        atomicAdd(&dh[bin], 1);
    }
    __syncthreads();
    if (t < 256 && dh[t]) atomicAdd(&ghist[t], dh[t]);
    rc[t] = base + ex;               // absolute write cursor per row
    __syncthreads();
    for (int i = t; i < n; i += 512) {
        unsigned pk = tp[i];
        int slot = atomicAdd(&rc[pk >> 18], 1);
        csrc[slot] = (int)(pk & 0x3FFFFu);
    }
}

// exclusive scan of 256-bin degree histogram -> gcur; zero work counters
__global__ __launch_bounds__(256) void k_dscan(const int* __restrict__ ghist,
                                               int* __restrict__ gcur,
                                               int* __restrict__ ctrs) {
    __shared__ int s[256];
    const int t = threadIdx.x;
    int v = ghist[t];
    s[t] = v;
    __syncthreads();
    for (int off = 1; off < 256; off <<= 1) {
        int u = (t >= off) ? s[t - off] : 0;
        __syncthreads();
        s[t] += u;
        __syncthreads();
    }
    gcur[t] = s[t] - v;
    if (t < 8) ctrs[t] = 0;
}

// LDS-staged scatter of rows into degree-sorted permutation
__global__ __launch_bounds__(512) void k_permscat(const int* __restrict__ rowptr,
                                                  int* __restrict__ gcur,
                                                  int* __restrict__ perm) {
    __shared__ int cnt[256];
    __shared__ int base_[256];
    const int b = blockIdx.x;
    const int t = threadIdx.x;
    if (t < 256) cnt[t] = 0;
    __syncthreads();
    int r = b * RPB + t;
    int bin = -1;
    if (r < N_NODES) {
        int deg = rowptr[r + 1] - rowptr[r];
        bin = deg > 255 ? 255 : deg;
        atomicAdd(&cnt[bin], 1);
    }
    __syncthreads();
    if (t < 256) {
        base_[t] = cnt[t] ? atomicAdd(&gcur[t], cnt[t]) : 0;
        cnt[t] = 0;
    }
    __syncthreads();
    if (r < N_NODES) {
        int pos = base_[bin] + atomicAdd(&cnt[bin], 1);
        perm[pos] = r;
    }
}

// F0 = dinv * E0, bf16
__global__ void k_cast(const float* __restrict__ E0, const float* __restrict__ dinv,
                       unsigned short* __restrict__ F0) {
    int i = blockIdx.x * blockDim.x + threadIdx.x;  // one float4 per thread
    const int total = N_NODES * EMB / 4;
    if (i >= total) return;
    float dv = dinv[i >> 4];
    float4 v = ((const float4*)E0)[i];
    ushort4 o;
    o.x = f2b(dv * v.x); o.y = f2b(dv * v.y);
    o.z = f2b(dv * v.z); o.w = f2b(dv * v.w);
    ((ushort4*)F0)[i] = o;
}

// ---------------- SpMM core: sum_{c in N(r)} F_in[c], 8 lanes/row ----------

__device__ __forceinline__ void spmm_row(const unsigned short* __restrict__ Fin,
                                         unsigned short* __restrict__ Fout,
                                         const int* __restrict__ cols,
                                         int beg, int end, int g, int lane, float s) {
    float A[8] = {0,0,0,0,0,0,0,0};
    float B[8] = {0,0,0,0,0,0,0,0};
    int j = beg;
    int nscal = (4 - (j & 3)) & 3;   // align to int4
    for (int k = 0; k < nscal && j < end; ++k, ++j) {
        uint4 v = ((const uint4*)(Fin + (size_t)cols[j] * EMB))[lane];
        acc8(A, v);
    }
    for (; j + 8 <= end; j += 8) {
        int4 c0 = *(const int4*)(cols + j);
        int4 c1 = *(const int4*)(cols + j + 4);
        uint4 v0 = ((const uint4*)(Fin + (size_t)c0.x * EMB))[lane];
        uint4 v1 = ((const uint4*)(Fin + (size_t)c0.y * EMB))[lane];
        uint4 v2 = ((const uint4*)(Fin + (size_t)c0.z * EMB))[lane];
        uint4 v3 = ((const uint4*)(Fin + (size_t)c0.w * EMB))[lane];
        uint4 v4 = ((const uint4*)(Fin + (size_t)c1.x * EMB))[lane];
        uint4 v5 = ((const uint4*)(Fin + (size_t)c1.y * EMB))[lane];
        uint4 v6 = ((const uint4*)(Fin + (size_t)c1.z * EMB))[lane];
        uint4 v7 = ((const uint4*)(Fin + (size_t)c1.w * EMB))[lane];
        acc8(A, v0); acc8(B, v1); acc8(A, v2); acc8(B, v3);
        acc8(A, v4); acc8(B, v5); acc8(A, v6); acc8(B, v7);
    }
    for (; j + 4 <= end; j += 4) {
        int4 c = *(const int4*)(cols + j);
        uint4 v0 = ((const uint4*)(Fin + (size_t)c.x * EMB))[lane];
        uint4 v1 = ((const uint4*)(Fin + (size_t)c.y * EMB))[lane];
        uint4 v2 = ((const uint4*)(Fin + (size_t)c.z * EMB))[lane];
        uint4 v3 = ((const uint4*)(Fin + (size_t)c.w * EMB))[lane];
        acc8(A, v0); acc8(B, v1); acc8(A, v2); acc8(B, v3);
    }
    for (; j < end; ++j) {
        uint4 v = ((const uint4*)(Fin + (size_t)cols[j] * EMB))[lane];
        acc8(A, v);
    }
    unsigned o0 = ((unsigned)f2b(s * (A[1] + B[1])) << 16) | f2b(s * (A[0] + B[0]));
    unsigned o1 = ((unsigned)f2b(s * (A[3] + B[3])) << 16) | f2b(s * (A[2] + B[2]));
    unsigned o2 = ((unsigned)f2b(s * (A[5] + B[5])) << 16) | f2b(s * (A[4] + B[4]));
    unsigned o3 = ((unsigned)f2b(s * (A[7] + B[7])) << 16) | f2b(s * (A[6] + B[6]));
    ((uint4*)(Fout + (size_t)g * EMB))[lane] = make_uint4(o0, o1, o2, o3);
}

// dense hop: persistent blocks, dynamic chunk queue, degree-sorted perm
__global__ __launch_bounds__(256) void k_spmm(const unsigned short* __restrict__ Fin,
                                              unsigned short* __restrict__ Fout,
                                              const int* __restrict__ rowptr,
                                              const int* __restrict__ cols,
                                              const float* __restrict__ s2,
                                              const int* __restrict__ perm,
                                              int* __restrict__ ctr) {
    __shared__ int chnk;
    const int lane = threadIdx.x & 7;
    const int grp  = threadIdx.x >> 3;  // 0..31
    for (;;) {
        if (threadIdx.x == 0) chnk = atomicAdd(ctr, 1);
        __syncthreads();
        int c = chnk;
        __syncthreads();
        if (c >= NCHUNK) break;
        int idx = c * CHROWS + grp;
        if (idx < N_NODES) {
            int g = perm[idx];
            spmm_row(Fin, Fout, cols, rowptr[g], rowptr[g + 1], g, lane, s2[g]);
        }
    }
}

// sparse hop 3: only batch rows (duplicates write identical values - benign)
__global__ __launch_bounds__(256) void k_spmm3(const unsigned short* __restrict__ Fin,
                                               unsigned short* __restrict__ Fout,
                                               const int* __restrict__ rowptr,
                                               const int* __restrict__ cols,
                                               const float* __restrict__ s2,
                                               const int* __restrict__ ub,
                                               const int* __restrict__ ib) {
    int gi   = (blockIdx.x * blockDim.x + threadIdx.x) >> 3;
    int lane = threadIdx.x & 7;
    if (gi >= 2 * BATCH) return;
    int g = (gi < BATCH) ? ub[gi] : (N_USERS + ib[gi - BATCH]);
    spmm_row(Fin, Fout, cols, rowptr[g], rowptr[g + 1], g, lane, s2[g]);
}

// ---------------- batch-row gather ----------------

__global__ void k_gather_init(const float* __restrict__ E0, const int* __restrict__ ub,
                              const int* __restrict__ ib, float* __restrict__ U,
                              float* __restrict__ I) {
    int g    = (blockIdx.x * blockDim.x + threadIdx.x) >> 4;
    int lane = threadIdx.x & 15;
    if (g >= 2 * BATCH) return;
    if (g < BATCH) {
        int r = ub[g];
        ((float4*)(U + (size_t)g * EMB))[lane] =
            ((const float4*)(E0 + (size_t)r * EMB))[lane];
    } else {
        int bq = g - BATCH;
        int r = N_USERS + ib[bq];
        ((float4*)(I + (size_t)bq * EMB))[lane] =
            ((const float4*)(E0 + (size_t)r * EMB))[lane];
    }
}

// U/I += F[r] * srt[r]   (recovers E_i[r] = F_i[r]/dinv[r])
__global__ void k_gather_acc(const unsigned short* __restrict__ F,
                             const float* __restrict__ srt,
                             const int* __restrict__ ub, const int* __restrict__ ib,
                             float* __restrict__ U, float* __restrict__ I) {
    int g    = (blockIdx.x * blockDim.x + threadIdx.x) >> 4;
    int lane = threadIdx.x & 15;
    if (g >= 2 * BATCH) return;
    int r, bq;
    float* dstbuf;
    if (g < BATCH) { r = ub[g]; bq = g; dstbuf = U; }
    else { bq = g - BATCH; r = N_USERS + ib[bq]; dstbuf = I; }
    float sr = srt[r];
    uint2 v = ((const uint2*)(F + (size_t)r * EMB))[lane];
    float4* dst = (float4*)(dstbuf + (size_t)bq * EMB) + lane;
    float4 a = *dst;
    a.x = fmaf(sr, b2f_lo(v.x), a.x); a.y = fmaf(sr, b2f_hi(v.x), a.y);
    a.z = fmaf(sr, b2f_lo(v.y), a.z); a.w = fmaf(sr, b2f_hi(v.y), a.w);
    *dst = a;
}

// ---------------- fused hop-3 accumulate + dot ----------------

__global__ void k_finish(const unsigned short* __restrict__ F3,
                         const float* __restrict__ srt,
                         const int* __restrict__ ub, const int* __restrict__ ib,
                         const float* __restrict__ U, const float* __restrict__ I,
                         float* __restrict__ out) {
    int q    = (blockIdx.x * blockDim.x + threadIdx.x) >> 4;
    int lane = threadIdx.x & 15;
    if (q >= BATCH) return;
    int u  = ub[q];
    int iv = N_USERS + ib[q];
    float su = srt[u], si = srt[iv];
    float4 a = ((const float4*)(U + (size_t)q * EMB))[lane];
    float4 b = ((const float4*)(I + (size_t)q * EMB))[lane];
    uint2 vu = ((const uint2*)(F3 + (size_t)u * EMB))[lane];
    uint2 vi = ((const uint2*)(F3 + (size_t)iv * EMB))[lane];
    a.x = fmaf(su, b2f_lo(vu.x), a.x); a.y = fmaf(su, b2f_hi(vu.x), a.y);
    a.z = fmaf(su, b2f_lo(vu.y), a.z); a.w = fmaf(su, b2f_hi(vu.y), a.w);
    b.x = fmaf(si, b2f_lo(vi.x), b.x); b.y = fmaf(si, b2f_hi(vi.x), b.y);
    b.z = fmaf(si, b2f_lo(vi.y), b.z); b.w = fmaf(si, b2f_hi(vi.y), b.w);
    float p = a.x * b.x + a.y * b.y + a.z * b.z + a.w * b.w;
    for (int m = 1; m < 16; m <<= 1) p += __shfl_xor(p, m, 64);
    if (lane == 0) out[q] = p * (1.0f / 16.0f);  // 1/(K+1)^2
}

// ---------------- launch ----------------

static inline char* align16(char* p) {
    return (char*)(((uintptr_t)p + 15) & ~(uintptr_t)15);
}

extern "C" void kernel_launch(void* const* d_in, const int* in_sizes, int n_in,
                              void* d_out, int out_size, void* d_ws, size_t ws_size,
                              hipStream_t stream) {
    const float* E0   = (const float*)d_in[0];
    const int*   erow = (const int*)d_in[2];
    const int*   ecol = (const int*)d_in[3];
    const int*   ub   = (const int*)d_in[4];
    const int*   ib   = (const int*)d_in[5];
    float* pred = (float*)d_out;

    char* p = (char*)d_ws;
    unsigned short* F0  = (unsigned short*)p; p = align16(p + (size_t)N_NODES * EMB * 2);
    unsigned short* Abf = (unsigned short*)p; p = align16(p + (size_t)N_NODES * EMB * 2);
    unsigned short* Bbf = (unsigned short*)p; p = align16(p + (size_t)N_NODES * EMB * 2);
    float* U       = (float*)p;    p = align16(p + (size_t)BATCH * EMB * 4);
    float* I       = (float*)p;    p = align16(p + (size_t)BATCH * EMB * 4);
    int*   bcursor = (int*)p;      p = align16(p + (size_t)NBKT * 4);
    int*   bbase   = (int*)p;      p = align16(p + (size_t)(NBKT + 1) * 4);
    int*   rowptr  = (int*)p;      p = align16(p + (size_t)(N_NODES + 1) * 4);
    float* dinv    = (float*)p;    p = align16(p + (size_t)N_NODES * 4);
    float* s2      = (float*)p;    p = align16(p + (size_t)N_NODES * 4);
    float* srt     = (float*)p;    p = align16(p + (size_t)N_NODES * 4);
    int*   ghist   = (int*)p;      p = align16(p + 256 * 4);
    int*   gcur    = (int*)p;      p = align16(p + 256 * 4);
    int*   ctrs    = (int*)p;      p = align16(p + 8 * 4);
    int*   perm    = (int*)p;      p = align16(p + (size_t)N_NODES * 4);
    int*   csrc    = (int*)p;      p = align16(p + (size_t)NEDGES * 4);
    unsigned* tmp  = (unsigned*)p; p = align16(p + (size_t)NBKT * BCAP * 4);

    const int BS = 256;
    // CSR build + degree-sort
    k_zero<<<(NBKT + BS - 1) / BS, BS, 0, stream>>>(bcursor, ghist);
    k_partC<<<PC_NWG, PC_BS, 0, stream>>>(erow, ecol, bcursor, tmp);
    k_bscan<<<1, 512, 0, stream>>>(bcursor, bbase, rowptr);
    k_rows_place<<<NBKT, 512, 0, stream>>>(tmp, bcursor, bbase, rowptr, dinv, s2, srt,
                                           csrc, ghist);
    k_dscan<<<1, 256, 0, stream>>>(ghist, gcur, ctrs);
    k_permscat<<<NBKT, 512, 0, stream>>>(rowptr, gcur, perm);
    k_cast<<<(N_NODES * EMB / 4 + BS - 1) / BS, BS, 0, stream>>>(E0, dinv, F0);

    k_gather_init<<<(2 * BATCH * 16 + BS - 1) / BS, BS, 0, stream>>>(E0, ub, ib, U, I);

    const int acc_grid = (2 * BATCH * 16 + BS - 1) / BS;
    const int spmm_blocks = 2048;

    // hop 1: F0 -> Abf (dense, degree-sorted + dynamic queue)
    k_spmm<<<spmm_blocks, BS, 0, stream>>>(F0, Abf, rowptr, csrc, s2, perm, ctrs + 0);
    k_gather_acc<<<acc_grid, BS, 0, stream>>>(Abf, srt, ub, ib, U, I);
    // hop 2: Abf -> Bbf (dense)
    k_spmm<<<spmm_blocks, BS, 0, stream>>>(Abf, Bbf, rowptr, csrc, s2, perm, ctrs + 1);
    k_gather_acc<<<acc_grid, BS, 0, stream>>>(Bbf, srt, ub, ib, U, I);
    // hop 3: Bbf -> Abf, batch rows only
    k_spmm3<<<(2 * BATCH * 8 + BS - 1) / BS, BS, 0, stream>>>(Bbf, Abf, rowptr, csrc,
                                                              s2, ub, ib);
    // fused hop-3 accumulate + dot
    k_finish<<<(BATCH * 16 + BS - 1) / BS, BS, 0, stream>>>(Abf, srt, ub, ib, U, I, pred);
}

// Round 9
// 245.914 us; speedup vs baseline: 1.3680x; 1.3680x over previous
//
#include <hip/hip_runtime.h>

#define N_USERS 100000
#define N_ITEMS 50000
#define N_NODES 150000
#define NEDGES  4000000
#define EMB     64
#define BATCH   16384

#define RSHIFT  9
#define RPB     512                          // rows per bucket
#define NBKT    ((N_NODES + RPB - 1) / RPB)  // 293
#define BCAP    24576                        // max edges/bucket

#define PC_BS   1024
#define PC_CH   16384
#define PC_EPT  (PC_CH / PC_BS)                 // 16 edges/thread
#define PC_NWG  ((NEDGES + PC_CH - 1) / PC_CH)  // 245

// ---------------- helpers ----------------

typedef float f32x2 __attribute__((ext_vector_type(2)));

__device__ __forceinline__ unsigned short f2b(float f) {  // fp32 -> bf16 RNE
    unsigned u = __float_as_uint(f);
    return (unsigned short)((u + 0x7FFFu + ((u >> 16) & 1u)) >> 16);
}
__device__ __forceinline__ float b2f_lo(unsigned v) { return __uint_as_float(v << 16); }
__device__ __forceinline__ float b2f_hi(unsigned v) { return __uint_as_float(v & 0xFFFF0000u); }

// accumulate 8 bf16 (uint4) into 4 packed f32x2 accumulators (v_pk_add_f32)
__device__ __forceinline__ void acc8p(f32x2* a, uint4 v) {
    f32x2 p0, p1, p2, p3;
    p0.x = b2f_lo(v.x); p0.y = b2f_hi(v.x);
    p1.x = b2f_lo(v.y); p1.y = b2f_hi(v.y);
    p2.x = b2f_lo(v.z); p2.y = b2f_hi(v.z);
    p3.x = b2f_lo(v.w); p3.y = b2f_hi(v.w);
    a[0] += p0; a[1] += p1; a[2] += p2; a[3] += p3;
}

__device__ __forceinline__ uint4 ldF(const char* __restrict__ Fb, unsigned off) {
    return *(const uint4*)(Fb + off);
}

// ---------------- CSR build ----------------

__global__ void k_zero(int* __restrict__ bcursor) {
    int i = blockIdx.x * blockDim.x + threadIdx.x;
    if (i < NBKT) bcursor[i] = 0;
}

// LDS-staged bucket partition; edges cached in registers across the two passes
__global__ __launch_bounds__(PC_BS) void k_partC(const int* __restrict__ erow,
                                                 const int* __restrict__ ecol,
                                                 int* __restrict__ bcursor,
                                                 unsigned* __restrict__ tmp) {
    __shared__ int cnt[NBKT];
    __shared__ int base_[NBKT];
    const int t = threadIdx.x;
    for (int i = t; i < NBKT; i += PC_BS) cnt[i] = 0;
    __syncthreads();
    const int e0 = blockIdx.x * PC_CH;
    int rr[PC_EPT], cc[PC_EPT];
#pragma unroll
    for (int k = 0; k < PC_EPT; ++k) {
        int e = e0 + t + k * PC_BS;
        if (e < NEDGES) {
            rr[k] = erow[e];
            cc[k] = ecol[e];
            atomicAdd(&cnt[rr[k] >> RSHIFT], 1);
        } else rr[k] = -1;
    }
    __syncthreads();
    for (int i = t; i < NBKT; i += PC_BS) {
        base_[i] = cnt[i] ? atomicAdd(&bcursor[i], cnt[i]) : 0;
        cnt[i] = 0;
    }
    __syncthreads();
#pragma unroll
    for (int k = 0; k < PC_EPT; ++k) {
        if (rr[k] >= 0) {
            int b = rr[k] >> RSHIFT;
            int pos = base_[b] + atomicAdd(&cnt[b], 1);
            if (pos < BCAP)
                tmp[(size_t)b * BCAP + pos] =
                    ((unsigned)(rr[k] & (RPB - 1)) << 18) | (unsigned)cc[k];
        }
    }
}

// scan of per-bucket totals
__global__ __launch_bounds__(512) void k_bscan(const int* __restrict__ bcursor,
                                               int* __restrict__ bbase,
                                               int* __restrict__ rowptr) {
    __shared__ int s[512];
    const int t = threadIdx.x;
    int v = 0;
    if (t < NBKT) { v = bcursor[t]; if (v > BCAP) v = BCAP; }
    s[t] = v;
    __syncthreads();
    for (int off = 1; off < 512; off <<= 1) {
        int u = (t >= off) ? s[t - off] : 0;
        __syncthreads();
        s[t] += u;
        __syncthreads();
    }
    if (t < NBKT) bbase[t] = s[t] - v;  // exclusive
    if (t == 511) { bbase[NBKT] = s[511]; rowptr[N_NODES] = s[511]; }
}

// fused: row count (LDS) -> LDS scan -> rowptr + dinv/s2/srt -> place edges
__global__ __launch_bounds__(512) void k_rows_place(const unsigned* __restrict__ tmp,
                                                    const int* __restrict__ bcursor,
                                                    const int* __restrict__ bbase,
                                                    int* __restrict__ rowptr,
                                                    float* __restrict__ dinv,
                                                    float* __restrict__ s2,
                                                    float* __restrict__ srt,
                                                    int* __restrict__ csrc) {
    __shared__ int rc[RPB];
    __shared__ int pre[RPB];
    const int b = blockIdx.x;
    const int t = threadIdx.x;
    rc[t] = 0;
    __syncthreads();
    int n = bcursor[b]; if (n > BCAP) n = BCAP;
    const unsigned* tp = tmp + (size_t)b * BCAP;
    for (int i = t; i < n; i += 512) atomicAdd(&rc[tp[i] >> 18], 1);
    __syncthreads();
    int my = rc[t];
    pre[t] = my;
    __syncthreads();
    for (int off = 1; off < 512; off <<= 1) {
        int u = (t >= off) ? pre[t - off] : 0;
        __syncthreads();
        pre[t] += u;
        __syncthreads();
    }
    int ex   = pre[t] - my;
    int base = bbase[b];
    int r = b * RPB + t;
    if (r < N_NODES) {
        float sr = sqrtf((float)my) + 1e-6f;   // 1/dinv
        float dv = 1.0f / sr;
        rowptr[r] = base + ex;
        dinv[r] = dv;
        s2[r]   = dv * dv;
        srt[r]  = sr;
    }
    __syncthreads();
    rc[t] = base + ex;               // absolute write cursor per row
    __syncthreads();
    for (int i = t; i < n; i += 512) {
        unsigned pk = tp[i];
        int slot = atomicAdd(&rc[pk >> 18], 1);
        csrc[slot] = (int)(pk & 0x3FFFFu);
    }
}

// F0 = dinv * E0, bf16
__global__ void k_cast(const float* __restrict__ E0, const float* __restrict__ dinv,
                       unsigned short* __restrict__ F0) {
    int i = blockIdx.x * blockDim.x + threadIdx.x;  // one float4 per thread
    const int total = N_NODES * EMB / 4;
    if (i >= total) return;
    float dv = dinv[i >> 4];
    float4 v = ((const float4*)E0)[i];
    ushort4 o;
    o.x = f2b(dv * v.x); o.y = f2b(dv * v.y);
    o.z = f2b(dv * v.z); o.w = f2b(dv * v.w);
    ((ushort4*)F0)[i] = o;
}

// ---------------- SpMM core: sum_{c in N(r)} F_in[c], 8 lanes/row ----------
// 32-bit byte offsets (F is 19.2 MB): off = c<<7 | lane<<4.

__device__ __forceinline__ void spmm_row(const unsigned short* __restrict__ Fin,
                                         unsigned short* __restrict__ Fout,
                                         const int* __restrict__ cols,
                                         int beg, int end, int g, int lane, float s) {
    const char* Fb = (const char*)Fin;
    const unsigned lb = (unsigned)lane << 4;
    f32x2 A[4], B[4];
#pragma unroll
    for (int k = 0; k < 4; ++k) { A[k] = (f32x2)0.0f; B[k] = (f32x2)0.0f; }
    int j = beg;
    int nscal = (4 - (j & 3)) & 3;   // align to int4
    for (int k = 0; k < nscal && j < end; ++k, ++j) {
        acc8p(A, ldF(Fb, ((unsigned)cols[j] << 7) | lb));
    }
    for (; j + 8 <= end; j += 8) {
        int4 c0 = *(const int4*)(cols + j);
        int4 c1 = *(const int4*)(cols + j + 4);
        uint4 v0 = ldF(Fb, ((unsigned)c0.x << 7) | lb);
        uint4 v1 = ldF(Fb, ((unsigned)c0.y << 7) | lb);
        uint4 v2 = ldF(Fb, ((unsigned)c0.z << 7) | lb);
        uint4 v3 = ldF(Fb, ((unsigned)c0.w << 7) | lb);
        uint4 v4 = ldF(Fb, ((unsigned)c1.x << 7) | lb);
        uint4 v5 = ldF(Fb, ((unsigned)c1.y << 7) | lb);
        uint4 v6 = ldF(Fb, ((unsigned)c1.z << 7) | lb);
        uint4 v7 = ldF(Fb, ((unsigned)c1.w << 7) | lb);
        acc8p(A, v0); acc8p(B, v1); acc8p(A, v2); acc8p(B, v3);
        acc8p(A, v4); acc8p(B, v5); acc8p(A, v6); acc8p(B, v7);
    }
    for (; j + 4 <= end; j += 4) {
        int4 c = *(const int4*)(cols + j);
        uint4 v0 = ldF(Fb, ((unsigned)c.x << 7) | lb);
        uint4 v1 = ldF(Fb, ((unsigned)c.y << 7) | lb);
        uint4 v2 = ldF(Fb, ((unsigned)c.z << 7) | lb);
        uint4 v3 = ldF(Fb, ((unsigned)c.w << 7) | lb);
        acc8p(A, v0); acc8p(B, v1); acc8p(A, v2); acc8p(B, v3);
    }
    for (; j < end; ++j) {
        acc8p(A, ldF(Fb, ((unsigned)cols[j] << 7) | lb));
    }
#pragma unroll
    for (int k = 0; k < 4; ++k) A[k] += B[k];
    unsigned o0 = ((unsigned)f2b(s * A[0].y) << 16) | f2b(s * A[0].x);
    unsigned o1 = ((unsigned)f2b(s * A[1].y) << 16) | f2b(s * A[1].x);
    unsigned o2 = ((unsigned)f2b(s * A[2].y) << 16) | f2b(s * A[2].x);
    unsigned o3 = ((unsigned)f2b(s * A[3].y) << 16) | f2b(s * A[3].x);
    ((uint4*)(Fout + (size_t)g * EMB))[lane >> 1 << 1 ? 0 : 0] =
        make_uint4(o0, o1, o2, o3);  // placeholder avoided below
}

// NOTE: the store above must be per-lane; use explicit function instead.
__device__ __forceinline__ void spmm_row_st(const unsigned short* __restrict__ Fin,
                                            unsigned short* __restrict__ Fout,
                                            const int* __restrict__ cols,
                                            int beg, int end, int g, int lane, float s) {
    const char* Fb = (const char*)Fin;
    const unsigned lb = (unsigned)lane << 4;
    f32x2 A[4], B[4];
#pragma unroll
    for (int k = 0; k < 4; ++k) { A[k] = (f32x2)0.0f; B[k] = (f32x2)0.0f; }
    int j = beg;
    int nscal = (4 - (j & 3)) & 3;
    for (int k = 0; k < nscal && j < end; ++k, ++j)
        acc8p(A, ldF(Fb, ((unsigned)cols[j] << 7) | lb));
    for (; j + 8 <= end; j += 8) {
        int4 c0 = *(const int4*)(cols + j);
        int4 c1 = *(const int4*)(cols + j + 4);
        uint4 v0 = ldF(Fb, ((unsigned)c0.x << 7) | lb);
        uint4 v1 = ldF(Fb, ((unsigned)c0.y << 7) | lb);
        uint4 v2 = ldF(Fb, ((unsigned)c0.z << 7) | lb);
        uint4 v3 = ldF(Fb, ((unsigned)c0.w << 7) | lb);
        uint4 v4 = ldF(Fb, ((unsigned)c1.x << 7) | lb);
        uint4 v5 = ldF(Fb, ((unsigned)c1.y << 7) | lb);
        uint4 v6 = ldF(Fb, ((unsigned)c1.z << 7) | lb);
        uint4 v7 = ldF(Fb, ((unsigned)c1.w << 7) | lb);
        acc8p(A, v0); acc8p(B, v1); acc8p(A, v2); acc8p(B, v3);
        acc8p(A, v4); acc8p(B, v5); acc8p(A, v6); acc8p(B, v7);
    }
    for (; j + 4 <= end; j += 4) {
        int4 c = *(const int4*)(cols + j);
        uint4 v0 = ldF(Fb, ((unsigned)c.x << 7) | lb);
        uint4 v1 = ldF(Fb, ((unsigned)c.y << 7) | lb);
        uint4 v2 = ldF(Fb, ((unsigned)c.z << 7) | lb);
        uint4 v3 = ldF(Fb, ((unsigned)c.w << 7) | lb);
        acc8p(A, v0); acc8p(B, v1); acc8p(A, v2); acc8p(B, v3);
    }
    for (; j < end; ++j)
        acc8p(A, ldF(Fb, ((unsigned)cols[j] << 7) | lb));
#pragma unroll
    for (int k = 0; k < 4; ++k) A[k] += B[k];
    unsigned o0 = ((unsigned)f2b(s * A[0].y) << 16) | f2b(s * A[0].x);
    unsigned o1 = ((unsigned)f2b(s * A[1].y) << 16) | f2b(s * A[1].x);
    unsigned o2 = ((unsigned)f2b(s * A[2].y) << 16) | f2b(s * A[2].x);
    unsigned o3 = ((unsigned)f2b(s * A[3].y) << 16) | f2b(s * A[3].x);
    *(uint4*)((char*)Fout + (((unsigned)g << 7) | lb)) = make_uint4(o0, o1, o2, o3);
}

// dense hop: all rows, static order (preserves csrc streaming + phase locality)
__global__ __launch_bounds__(256) void k_spmm(const unsigned short* __restrict__ Fin,
                                              unsigned short* __restrict__ Fout,
                                              const int* __restrict__ rowptr,
                                              const int* __restrict__ cols,
                                              const float* __restrict__ s2) {
    int g    = (blockIdx.x * blockDim.x + threadIdx.x) >> 3;
    int lane = threadIdx.x & 7;
    if (g >= N_NODES) return;
    spmm_row_st(Fin, Fout, cols, rowptr[g], rowptr[g + 1], g, lane, s2[g]);
}

// sparse hop 3: only batch rows (duplicates write identical values - benign)
__global__ __launch_bounds__(256) void k_spmm3(const unsigned short* __restrict__ Fin,
                                               unsigned short* __restrict__ Fout,
                                               const int* __restrict__ rowptr,
                                               const int* __restrict__ cols,
                                               const float* __restrict__ s2,
                                               const int* __restrict__ ub,
                                               const int* __restrict__ ib) {
    int gi   = (blockIdx.x * blockDim.x + threadIdx.x) >> 3;
    int lane = threadIdx.x & 7;
    if (gi >= 2 * BATCH) return;
    int g = (gi < BATCH) ? ub[gi] : (N_USERS + ib[gi - BATCH]);
    spmm_row_st(Fin, Fout, cols, rowptr[g], rowptr[g + 1], g, lane, s2[g]);
}

// ---------------- batch-row gather ----------------

__global__ void k_gather_init(const float* __restrict__ E0, const int* __restrict__ ub,
                              const int* __restrict__ ib, float* __restrict__ U,
                              float* __restrict__ I) {
    int g    = (blockIdx.x * blockDim.x + threadIdx.x) >> 4;
    int lane = threadIdx.x & 15;
    if (g >= 2 * BATCH) return;
    if (g < BATCH) {
        int r = ub[g];
        ((float4*)(U + (size_t)g * EMB))[lane] =
            ((const float4*)(E0 + (size_t)r * EMB))[lane];
    } else {
        int bq = g - BATCH;
        int r = N_USERS + ib[bq];
        ((float4*)(I + (size_t)bq * EMB))[lane] =
            ((const float4*)(E0 + (size_t)r * EMB))[lane];
    }
}

// U/I += F[r] * srt[r]   (recovers E_i[r] = F_i[r]/dinv[r])
__global__ void k_gather_acc(const unsigned short* __restrict__ F,
                             const float* __restrict__ srt,
                             const int* __restrict__ ub, const int* __restrict__ ib,
                             float* __restrict__ U, float* __restrict__ I) {
    int g    = (blockIdx.x * blockDim.x + threadIdx.x) >> 4;
    int lane = threadIdx.x & 15;
    if (g >= 2 * BATCH) return;
    int r, bq;
    float* dstbuf;
    if (g < BATCH) { r = ub[g]; bq = g; dstbuf = U; }
    else { bq = g - BATCH; r = N_USERS + ib[bq]; dstbuf = I; }
    float sr = srt[r];
    uint2 v = ((const uint2*)(F + (size_t)r * EMB))[lane];
    float4* dst = (float4*)(dstbuf + (size_t)bq * EMB) + lane;
    float4 a = *dst;
    a.x = fmaf(sr, b2f_lo(v.x), a.x); a.y = fmaf(sr, b2f_hi(v.x), a.y);
    a.z = fmaf(sr, b2f_lo(v.y), a.z); a.w = fmaf(sr, b2f_hi(v.y), a.w);
    *dst = a;
}

// ---------------- fused hop-3 accumulate + dot ----------------

__global__ void k_finish(const unsigned short* __restrict__ F3,
                         const float* __restrict__ srt,
                         const int* __restrict__ ub, const int* __restrict__ ib,
                         const float* __restrict__ U, const float* __restrict__ I,
                         float* __restrict__ out) {
    int q    = (blockIdx.x * blockDim.x + threadIdx.x) >> 4;
    int lane = threadIdx.x & 15;
    if (q >= BATCH) return;
    int u  = ub[q];
    int iv = N_USERS + ib[q];
    float su = srt[u], si = srt[iv];
    float4 a = ((const float4*)(U + (size_t)q * EMB))[lane];
    float4 b = ((const float4*)(I + (size_t)q * EMB))[lane];
    uint2 vu = ((const uint2*)(F3 + (size_t)u * EMB))[lane];
    uint2 vi = ((const uint2*)(F3 + (size_t)iv * EMB))[lane];
    a.x = fmaf(su, b2f_lo(vu.x), a.x); a.y = fmaf(su, b2f_hi(vu.x), a.y);
    a.z = fmaf(su, b2f_lo(vu.y), a.z); a.w = fmaf(su, b2f_hi(vu.y), a.w);
    b.x = fmaf(si, b2f_lo(vi.x), b.x); b.y = fmaf(si, b2f_hi(vi.x), b.y);
    b.z = fmaf(si, b2f_lo(vi.y), b.z); b.w = fmaf(si, b2f_hi(vi.y), b.w);
    float p = a.x * b.x + a.y * b.y + a.z * b.z + a.w * b.w;
    for (int m = 1; m < 16; m <<= 1) p += __shfl_xor(p, m, 64);
    if (lane == 0) out[q] = p * (1.0f / 16.0f);  // 1/(K+1)^2
}

// ---------------- launch ----------------

static inline char* align16(char* p) {
    return (char*)(((uintptr_t)p + 15) & ~(uintptr_t)15);
}

extern "C" void kernel_launch(void* const* d_in, const int* in_sizes, int n_in,
                              void* d_out, int out_size, void* d_ws, size_t ws_size,
                              hipStream_t stream) {
    const float* E0   = (const float*)d_in[0];
    const int*   erow = (const int*)d_in[2];
    const int*   ecol = (const int*)d_in[3];
    const int*   ub   = (const int*)d_in[4];
    const int*   ib   = (const int*)d_in[5];
    float* pred = (float*)d_out;

    char* p = (char*)d_ws;
    unsigned short* F0  = (unsigned short*)p; p = align16(p + (size_t)N_NODES * EMB * 2);
    unsigned short* Abf = (unsigned short*)p; p = align16(p + (size_t)N_NODES * EMB * 2);
    unsigned short* Bbf = (unsigned short*)p; p = align16(p + (size_t)N_NODES * EMB * 2);
    float* U       = (float*)p;    p = align16(p + (size_t)BATCH * EMB * 4);
    float* I       = (float*)p;    p = align16(p + (size_t)BATCH * EMB * 4);
    int*   bcursor = (int*)p;      p = align16(p + (size_t)NBKT * 4);
    int*   bbase   = (int*)p;      p = align16(p + (size_t)(NBKT + 1) * 4);
    int*   rowptr  = (int*)p;      p = align16(p + (size_t)(N_NODES + 1) * 4);
    float* dinv    = (float*)p;    p = align16(p + (size_t)N_NODES * 4);
    float* s2      = (float*)p;    p = align16(p + (size_t)N_NODES * 4);
    float* srt     = (float*)p;    p = align16(p + (size_t)N_NODES * 4);
    int*   csrc    = (int*)p;      p = align16(p + (size_t)NEDGES * 4);
    unsigned* tmp  = (unsigned*)p; p = align16(p + (size_t)NBKT * BCAP * 4);

    const int BS = 256;
    // CSR build
    k_zero<<<(NBKT + BS - 1) / BS, BS, 0, stream>>>(bcursor);
    k_partC<<<PC_NWG, PC_BS, 0, stream>>>(erow, ecol, bcursor, tmp);
    k_bscan<<<1, 512, 0, stream>>>(bcursor, bbase, rowptr);
    k_rows_place<<<NBKT, 512, 0, stream>>>(tmp, bcursor, bbase, rowptr, dinv, s2, srt, csrc);
    k_cast<<<(N_NODES * EMB / 4 + BS - 1) / BS, BS, 0, stream>>>(E0, dinv, F0);

    k_gather_init<<<(2 * BATCH * 16 + BS - 1) / BS, BS, 0, stream>>>(E0, ub, ib, U, I);

    const int spmm_grid = (N_NODES * 8 + BS - 1) / BS;
    const int acc_grid  = (2 * BATCH * 16 + BS - 1) / BS;

    // hop 1: F0 -> Abf (dense)
    k_spmm<<<spmm_grid, BS, 0, stream>>>(F0, Abf, rowptr, csrc, s2);
    k_gather_acc<<<acc_grid, BS, 0, stream>>>(Abf, srt, ub, ib, U, I);
    // hop 2: Abf -> Bbf (dense)
    k_spmm<<<spmm_grid, BS, 0, stream>>>(Abf, Bbf, rowptr, csrc, s2);
    k_gather_acc<<<acc_grid, BS, 0, stream>>>(Bbf, srt, ub, ib, U, I);
    // hop 3: Bbf -> Abf, batch rows only
    k_spmm3<<<(2 * BATCH * 8 + BS - 1) / BS, BS, 0, stream>>>(Bbf, Abf, rowptr, csrc,
                                                              s2, ub, ib);
    // fused hop-3 accumulate + dot
    k_finish<<<(BATCH * 16 + BS - 1) / BS, BS, 0, stream>>>(Abf, srt, ub, ib, U, I, pred);
}